// Round 10
// baseline (266.303 us; speedup 1.0000x reference)
//
#include <hip/hip_runtime.h>
#include <math.h>

#define Bsz 4
#define Tsz 2048
#define Csz 1024
#define NH  16
#define HD  64

typedef short bf16x8 __attribute__((ext_vector_type(8)));
typedef float f32x4  __attribute__((ext_vector_type(4)));
typedef unsigned short u16;
typedef unsigned int uint;

__device__ __forceinline__ u16 f2bf(float f) {
    union { float f; unsigned u; } v; v.f = f;
    unsigned r = v.u + 0x7fffu + ((v.u >> 16) & 1u);
    return (u16)(r >> 16);
}

__device__ __forceinline__ uint pkbf(float a, float b) {
    union { float f; uint u; } x, y; x.f = a; y.f = b;
    return ((x.u + 0x8000u) >> 16) | ((y.u + 0x8000u) & 0xFFFF0000u);
}

// async global->LDS, 16B per lane. LDS dest is wave-uniform base + lane*16B.
__device__ __forceinline__ void glds16(const u16* g, u16* l) {
    __builtin_amdgcn_global_load_lds(
        (const __attribute__((address_space(1))) void*)g,
        (__attribute__((address_space(3))) void*)l, 16, 0, 0);
}

// ---------------- fused cast (x + 4 weight matrices, one launch) ----------------
__global__ void cast_all(const float* __restrict__ x,
                         const float* __restrict__ s0, const float* __restrict__ s1,
                         const float* __restrict__ s2, const float* __restrict__ s3,
                         u16* __restrict__ xb, u16* __restrict__ wdst) {
    const int NW = Csz * Csz;
    const size_t NX = (size_t)Bsz * Tsz * Csz;
    size_t i = ((size_t)blockIdx.x * blockDim.x + threadIdx.x) * 8;
    const float* src;
    u16* dst;
    if (i < NX) {
        src = x + i; dst = xb + i;
    } else {
        size_t j = i - NX;
        int m = (int)(j >> 20);
        size_t local = j & (NW - 1);
        src = ((m == 0) ? s0 : (m == 1) ? s1 : (m == 2) ? s2 : s3) + local;
        dst = wdst + j;
    }
    float4 a = *(const float4*)(src);
    float4 b = *(const float4*)(src + 4);
    bf16x8 o;
    o[0] = (short)f2bf(a.x); o[1] = (short)f2bf(a.y);
    o[2] = (short)f2bf(a.z); o[3] = (short)f2bf(a.w);
    o[4] = (short)f2bf(b.x); o[5] = (short)f2bf(b.y);
    o[6] = (short)f2bf(b.z); o[7] = (short)f2bf(b.w);
    *(bf16x8*)(dst) = o;
}

// ================= 128x256 2-phase-per-K-tile GEMM template =================
// (unchanged — vmcnt(6) steady / {3,0} tail; bank swizzle on glds source + read)

#define G2_SS 24576

#define G2_STAGEA(SLOT, KH, KT, PTR) {                                               \
    const int row_ = tid >> 2;                                                       \
    const int sc_ = (tid & 3) ^ ((row_ >> 1) & 3);                                   \
    glds16((PTR) + (size_t)row_ * 1024 + (KT) * 64 + (KH) * 32 + sc_ * 8,            \
           lds + (SLOT) * G2_SS + (KH) * 4096 + wave * 512); }

#define G2_STAGEB(SLOT, KH, KT, PTR) {                                               \
    _Pragma("unroll")                                                                \
    for (int rho = 0; rho < 2; rho++) {                                              \
        const int row_ = rho * 128 + (tid >> 2);                                     \
        const int sc_ = (tid & 3) ^ ((row_ >> 1) & 3);                               \
        glds16((PTR) + (size_t)row_ * 1024 + (KT) * 64 + (KH) * 32 + sc_ * 8,        \
               lds + (SLOT) * G2_SS + 8192 + (KH) * 8192 + rho * 4096 + wave * 512); } }

#define G2_PHASE(SLOT, KH, STAGE)                                                    \
    {                                                                                \
        __builtin_amdgcn_s_barrier();                                                \
        asm volatile("" ::: "memory");                                               \
        STAGE                                                                        \
        const u16* abase = lds + (SLOT) * G2_SS + (KH) * 4096;                       \
        const u16* bbase = lds + (SLOT) * G2_SS + 8192 + (KH) * 8192;                \
        bf16x8 afr[4], bfr[4];                                                       \
        _Pragma("unroll")                                                            \
        for (int i = 0; i < 4; i++) {                                                \
            const int ar = wrb + i * 16 + lr;                                        \
            afr[i] = *(const bf16x8*)(abase + ar * 32 +                              \
                                      ((lq ^ ((ar >> 1) & 3)) * 8));                 \
        }                                                                            \
        _Pragma("unroll")                                                            \
        for (int j = 0; j < 4; j++) {                                                \
            const int nr = wcb + j * 16 + lr;                                        \
            bfr[j] = *(const bf16x8*)(bbase + nr * 32 +                              \
                                      ((lq ^ ((nr >> 1) & 3)) * 8));                 \
        }                                                                            \
        asm volatile("" ::: "memory");                                               \
        __builtin_amdgcn_s_setprio(1);                                               \
        _Pragma("unroll")                                                            \
        for (int i = 0; i < 4; i++)                                                  \
            _Pragma("unroll")                                                        \
            for (int j = 0; j < 4; j++)                                              \
                acc[i][j] = __builtin_amdgcn_mfma_f32_16x16x32_bf16(                 \
                    afr[i], bfr[j], acc[i][j], 0, 0, 0);                             \
        __builtin_amdgcn_s_setprio(0);                                               \
    }

#define G2_VM(N) asm volatile("s_waitcnt vmcnt(" #N ")" ::: "memory")

#define G2_BODY(AP_, BP_)                                                            \
    __shared__ u16 lds[49152];                                                       \
    const int tid = threadIdx.x;                                                     \
    const int wave = tid >> 6, lane = tid & 63;                                      \
    const int lr = lane & 15, lq = lane >> 4;                                        \
    const int wrb = (wave >> 2) * 64, wcb = (wave & 3) * 64;                         \
    f32x4 acc[4][4] = {};                                                            \
    G2_STAGEA(0, 0, 0, AP_) G2_STAGEB(0, 0, 0, BP_)                                  \
    G2_STAGEA(0, 1, 0, AP_) G2_STAGEB(0, 1, 0, BP_)                                  \
    G2_STAGEA(1, 0, 1, AP_) G2_STAGEB(1, 0, 1, BP_)                                  \
    for (int t = 0; t < 16; t++) {                                                   \
        const int s = t & 1;                                                         \
        if (t == 15) { G2_VM(3); } else { G2_VM(6); }                                \
        G2_PHASE(s, 0, if (t < 15) { G2_STAGEA(s ^ 1, 1, t + 1, AP_)                 \
                                     G2_STAGEB(s ^ 1, 1, t + 1, BP_) })              \
        if (t == 15) { G2_VM(0); } else { G2_VM(6); }                                \
        G2_PHASE(s, 1, if (t < 14) { G2_STAGEA(s, 0, t + 2, AP_)                     \
                                     G2_STAGEB(s, 0, t + 2, BP_) })                  \
    }

// ---------------- fused QKV GEMM ----------------
__global__ __launch_bounds__(512, 2)
void gemm_qkv(const u16* __restrict__ A, const u16* __restrict__ Bm,
              u16* __restrict__ Qo, u16* __restrict__ Ko, u16* __restrict__ Vo,
              float qscale) {
    const int wg = blockIdx.x;
    const int chunk = wg & 7, pos = wg >> 3;            // chunk = XCD, pos 0..95
    const int m0 = ((chunk >> 1) * 16 + pos / 6) * 128;
    const int n0 = ((chunk & 1) * 6 + pos % 6) * 256;
    const u16* Ap = A  + (size_t)m0 * 1024;
    const u16* Bp = Bm + (size_t)n0 * 1024;

    G2_BODY(Ap, Bp)

    const int sel = n0 >> 10;   // block-uniform: 0=Q, 1=K, 2=V
    if (sel == 2) {
        #pragma unroll
        for (int mi = 0; mi < 4; mi++) {
            #pragma unroll
            for (int ni = 0; ni < 4; ni++) {
                int m = m0 + wrb + mi * 16 + lq * 4;
                int b = m >> 11, tt = m & (Tsz - 1);
                int n = (n0 & 1023) + wcb + ni * 16 + lr;
                int h = n >> 6, d = n & (HD - 1);
                uint2 pk;
                pk.x = pkbf(acc[mi][ni][0], acc[mi][ni][1]);
                pk.y = pkbf(acc[mi][ni][2], acc[mi][ni][3]);
                *(uint2*)(&Vo[(((size_t)b * NH + h) * HD + d) * Tsz + tt]) = pk;
            }
        }
    } else {
        const float scale = (sel == 0) ? qscale : 1.0f;
        u16* dst = (sel == 0) ? Qo : Ko;
        #pragma unroll
        for (int mi = 0; mi < 4; mi++)
            #pragma unroll
            for (int ni = 0; ni < 4; ni++)
                #pragma unroll
                for (int r = 0; r < 4; r++) {
                    int m = m0 + wrb + mi * 16 + lq * 4 + r;
                    int n = (n0 & 1023) + wcb + ni * 16 + lr;
                    int b = m >> 11, tt = m & (Tsz - 1);
                    int h = n >> 6,  d = n & (HD - 1);
                    dst[(((size_t)b * NH + h) * Tsz + tt) * HD + d] = f2bf(acc[mi][ni][r] * scale);
                }
    }
}

// ---------------- output projection GEMM ----------------
__global__ __launch_bounds__(512, 2)
void gemm_out(const u16* __restrict__ A, const u16* __restrict__ Bm,
              float* __restrict__ out) {
    const int wg = blockIdx.x;
    const int chunk = wg & 7, pos = wg >> 3;            // pos 0..31
    const int m0 = (chunk * 8 + (pos >> 2)) * 128;
    const int n0 = (pos & 3) * 256;
    const u16* Ap = A  + (size_t)m0 * 1024;
    const u16* Bp = Bm + (size_t)n0 * 1024;

    G2_BODY(Ap, Bp)

    #pragma unroll
    for (int mi = 0; mi < 4; mi++)
        #pragma unroll
        for (int ni = 0; ni < 4; ni++)
            #pragma unroll
            for (int r = 0; r < 4; r++) {
                int m = m0 + wrb + mi * 16 + lq * 4 + r;
                int n = n0 + wcb + ni * 16 + lr;
                out[(size_t)m * Csz + n] = acc[mi][ni][r];
            }
}

// ---------------- flash attention ----------------
// Round-10 change: one-iteration P/V lag (T15 compute[cur] || finish[prev]).
// Iteration kb: stage K[kb],V[kb] -> QK(kb) -> PV(kb-1) -> exp(kb) -> write sP.
// The P LDS write->read turnaround (previously on EVERY iteration's critical
// path: write, lgkm drain, read before PV could start) now spans
// barrier+staging+QK of the next iteration -> fully hidden. PV MFMAs overlap
// exp's VALU on separate pipes.
//  - sV double-buffered (PV(kb-1) needs V[kb-1] after V[kb] staged): WAR safe,
//    sV[kb&1] overwrites V[kb-2] whose reads finished in iter kb-1 (barrier).
//  - sP single-buffered per-wave: pf read (kb-1) precedes this iter's
//    overwrite in program order; DS ops are per-wave in-order and the
//    compiler orders the aliasing accesses.
//  - LDS 35.5KB -> 4 blocks/CU (clear of round-5's 44.5KB occupancy cliff).
// FAILED perturbation log (do not repeat): r3 DIAG-split+setprio (77->88);
// r5 KVBLK=128 (77->87); r8 swapped-QK packed sP write (77->90).
#define LDT  72
#define LDTP 68

__global__ __launch_bounds__(256, 4)
void attn_kernel(const u16* __restrict__ Q, const u16* __restrict__ Kb,
                 const u16* __restrict__ Vt, u16* __restrict__ O) {
    __shared__ u16 sK[64 * LDT];
    __shared__ u16 sV[2][64 * LDT];
    __shared__ u16 sP[4][16 * LDTP];
    const int tid  = threadIdx.x;
    const int wave = tid >> 6, lane = tid & 63;
    const int lr = lane & 15, lq = lane >> 4;
    const int bh = blockIdx.x;           // 0..63  (XCD swizzle: id%8 == bh%8)
    const int tq = 31 - blockIdx.y;      // q-tile index; longest first (LPT)
    const int tc = tq * 64;

    const u16* Qp = Q  + (size_t)bh * Tsz * HD;
    const u16* Kp = Kb + (size_t)bh * Tsz * HD;
    const u16* Vp = Vt + (size_t)bh * HD * Tsz;

    bf16x8 qf0 = *(const bf16x8*)(Qp + (size_t)(tc + wave * 16 + lr) * HD + lq * 8);
    bf16x8 qf1 = *(const bf16x8*)(Qp + (size_t)(tc + wave * 16 + lr) * HD + 32 + lq * 8);

    f32x4 accO[4] = {};
    f32x4 accL = {};

    bf16x8 ones;
    #pragma unroll
    for (int i = 0; i < 8; i++) ones[i] = (short)0x3F80;  // bf16 1.0

    const int strow = tid >> 3;
    const int stcol = (tid & 7) * 8;
    const u16* gK0 = Kp + (size_t)strow * HD + stcol;
    const u16* gK1 = gK0 + 32 * HD;
    const u16* gV0 = Vp + (size_t)strow * Tsz + stcol;
    const u16* gV1 = gV0 + 32 * Tsz;
    u16* lK0 = sK + strow * LDT + stcol;  u16* lK1 = lK0 + 32 * LDT;

    bf16x8 pK0 = *(const bf16x8*)(gK0);
    bf16x8 pK1 = *(const bf16x8*)(gK1);
    bf16x8 pV0 = *(const bf16x8*)(gV0);
    bf16x8 pV1 = *(const bf16x8*)(gV1);

    u16* sPw = &sP[wave][0];

    for (int kb = 0; kb <= tq; kb++) {
        __syncthreads();   // prev iter's K/V reads complete (QK(kb-1), PV(kb-2))
        u16* lV = &sV[kb & 1][0] + strow * LDT + stcol;
        *(bf16x8*)lK0 = pK0; *(bf16x8*)lK1 = pK1;
        *(bf16x8*)lV  = pV0; *(bf16x8*)(lV + 32 * LDT) = pV1;
        __syncthreads();
        if (kb < tq) {
            pK0 = *(const bf16x8*)(gK0 + (size_t)(kb + 1) * 64 * HD);
            pK1 = *(const bf16x8*)(gK1 + (size_t)(kb + 1) * 64 * HD);
            pV0 = *(const bf16x8*)(gV0 + (kb + 1) * 64);
            pV1 = *(const bf16x8*)(gV1 + (kb + 1) * 64);
        }
        // ---- QK^T for tile kb ----
        f32x4 accS[4];
        #pragma unroll
        for (int j = 0; j < 4; j++) {
            bf16x8 b0 = *(const bf16x8*)(sK + (j * 16 + lr) * LDT + lq * 8);
            bf16x8 b1 = *(const bf16x8*)(sK + (j * 16 + lr) * LDT + 32 + lq * 8);
            f32x4 z = {};
            z = __builtin_amdgcn_mfma_f32_16x16x32_bf16(qf0, b0, z, 0, 0, 0);
            z = __builtin_amdgcn_mfma_f32_16x16x32_bf16(qf1, b1, z, 0, 0, 0);
            accS[j] = z;
        }
        // ---- PV for tile kb-1 (P written last iteration; V in other buffer) ----
        if (kb > 0) {
            const u16* sVp = &sV[(kb - 1) & 1][0];
            #pragma unroll
            for (int ks = 0; ks < 2; ks++) {
                bf16x8 pf = *(const bf16x8*)(sPw + lr * LDTP + ks * 32 + lq * 8);
                accL = __builtin_amdgcn_mfma_f32_16x16x32_bf16(pf, ones, accL, 0, 0, 0);
                #pragma unroll
                for (int j = 0; j < 4; j++) {
                    bf16x8 vf = *(const bf16x8*)(sVp + (j * 16 + lr) * LDT + ks * 32 + lq * 8);
                    accO[j] = __builtin_amdgcn_mfma_f32_16x16x32_bf16(pf, vf, accO[j], 0, 0, 0);
                }
            }
        }
        // ---- exp + write P[kb] (overwrites sP after the reads above) ----
        {
            const int DIAG = (kb == tq);
            #pragma unroll
            for (int r = 0; r < 4; r++) {
                const int rowg = tc + wave * 16 + lq * 4 + r;
                #pragma unroll
                for (int j = 0; j < 4; j++) {
                    float v = accS[j][r];
                    if (DIAG && (kb * 64 + j * 16 + lr > rowg)) v = -200.0f;
                    union { float f; uint u; } e;
                    e.f = __builtin_amdgcn_exp2f(v);
                    sPw[(lq * 4 + r) * LDTP + j * 16 + lr] = (u16)(e.u >> 16);
                }
            }
        }
    }
    // ---- epilogue: PV for tile tq ----
    {
        const u16* sVp = &sV[tq & 1][0];
        #pragma unroll
        for (int ks = 0; ks < 2; ks++) {
            bf16x8 pf = *(const bf16x8*)(sPw + lr * LDTP + ks * 32 + lq * 8);
            accL = __builtin_amdgcn_mfma_f32_16x16x32_bf16(pf, ones, accL, 0, 0, 0);
            #pragma unroll
            for (int j = 0; j < 4; j++) {
                bf16x8 vf = *(const bf16x8*)(sVp + (j * 16 + lr) * LDT + ks * 32 + lq * 8);
                accO[j] = __builtin_amdgcn_mfma_f32_16x16x32_bf16(pf, vf, accO[j], 0, 0, 0);
            }
        }
    }

    const int b = bh >> 4, h = bh & 15;
    #pragma unroll
    for (int j = 0; j < 4; j++) {
        #pragma unroll
        for (int r = 0; r < 4; r++) {
            int t = wave * 16 + lq * 4 + r;
            int d = j * 16 + lr;
            O[((size_t)b * Tsz + tc + t) * Csz + h * HD + d] = f2bf(accO[j][r] / accL[r]);
        }
    }
}

// ---------------- launcher ----------------
extern "C" void kernel_launch(void* const* d_in, const int* in_sizes, int n_in,
                              void* d_out, int out_size, void* d_ws, size_t ws_size,
                              hipStream_t stream) {
    const float* x  = (const float*)d_in[0];
    const float* Wq = (const float*)d_in[1];
    const float* Wk = (const float*)d_in[2];
    const float* Wv = (const float*)d_in[3];
    const float* Wo = (const float*)d_in[4];
    float* out = (float*)d_out;

    const size_t NX = (size_t)Bsz * Tsz * Csz;  // 8388608
    const size_t NW = (size_t)Csz * Csz;        // 1048576

    char* ws = (char*)d_ws;
    u16* xb   = (u16*)ws; ws += NX * 2;
    u16* wqkv = (u16*)ws; ws += 3 * NW * 2;
    u16* wob  = (u16*)ws; ws += NW * 2;         // contiguous after wqkv (cast target)
    u16* qbuf = (u16*)ws; ws += NX * 2;
    u16* kbuf = (u16*)ws; ws += NX * 2;
    u16* vtb  = (u16*)ws; ws += NX * 2;
    u16* abuf = (u16*)ws; ws += NX * 2;

    cast_all<<<dim3((unsigned)((NX + 4 * NW) / 2048)), 256, 0, stream>>>(
        x, Wq, Wk, Wv, Wo, xb, wqkv);

    const float qscale = 0.125f * 1.44269504088896340736f;  // 1/sqrt(64) * log2(e)
    gemm_qkv<<<dim3(768), 512, 0, stream>>>(xb, wqkv, qbuf, kbuf, vtb, qscale);

    attn_kernel<<<dim3(Bsz * NH, 32), 256, 0, stream>>>(qbuf, kbuf, vtb, abuf);

    gemm_out<<<dim3(256), 512, 0, stream>>>(abuf, wob, out);
}